// Round 2
// baseline (137.519 us; speedup 1.0000x reference)
//
#include <hip/hip_runtime.h>

// DB4: dec_lo[j] = h[7-j]; dec_hi[j] = (-1)^(j+1) * h[j]
static constexpr float LO[8] = {
    -0.010597401784997278f,  0.032883011666982945f,  0.030841381835986965f,
    -0.18703481171888114f,  -0.02798376941698385f,   0.6308807679295904f,
     0.7148465705525415f,    0.23037781330885523f
};
static constexpr float HI[8] = {
    -0.23037781330885523f,   0.7148465705525415f,   -0.6308807679295904f,
    -0.02798376941698385f,   0.18703481171888114f,   0.030841381835986965f,
    -0.032883011666982945f, -0.010597401784997278f
};

// One wave (64 lanes) owns one full row of 4096. Lane l owns elements
// [64l, 64l+64). All intermediates live in registers; periodic halos move
// via ring __shfl (the wave ring IS the circular boundary). No LDS, no
// __syncthreads. All array indices are compile-time (full unroll).
__global__ __launch_bounds__(256, 2)
void WaveletSeasonalDecomposer_43181601194295_kernel(const float* __restrict__ in,
                                                     float* __restrict__ seasonal,
                                                     float* __restrict__ residual)
{
    const int lane = threadIdx.x & 63;
    const int wave = threadIdx.x >> 6;
    const int row  = (blockIdx.x << 2) + wave;
    const int prev = (lane + 63) & 63;
    const int next = (lane + 1) & 63;

    const size_t rbase = (size_t)row * 4096 + (size_t)lane * 64;
    const float* xr = in + rbase;

    // ---- load lane chunk (per-lane contiguous 256B; lines fully consumed)
    float x[64];
    #pragma unroll
    for (int c = 0; c < 16; ++c) {
        const float4 v = *(const float4*)(xr + 4 * c);
        x[4 * c + 0] = v.x; x[4 * c + 1] = v.y;
        x[4 * c + 2] = v.z; x[4 * c + 3] = v.w;
    }

    // ---- Level 1 DWT: x(64) -> a1(32), d1(32).  a[i] = sum_j x[2i+1-j]*LO[j]
    float hx[6];
    #pragma unroll
    for (int k = 0; k < 6; ++k) hx[k] = __shfl(x[58 + k], prev, 64);

    float a1[32], d1[32];
    #pragma unroll
    for (int i = 0; i < 32; ++i) {
        float sa = 0.f, sd = 0.f;
        #pragma unroll
        for (int j = 0; j < 8; ++j) {
            const int idx = 2 * i + 1 - j;                       // [-6 .. 63]
            const float v = (idx >= 0) ? x[idx >= 0 ? idx : 0]
                                       : hx[idx < 0 ? idx + 6 : 0];
            sa = fmaf(v, LO[j], sa);
            sd = fmaf(v, HI[j], sd);
        }
        a1[i] = sa; d1[i] = sd;
    }

    // ---- Level 2 DWT: a1(32) -> a2(16), d2(16)
    float h2[6];
    #pragma unroll
    for (int k = 0; k < 6; ++k) h2[k] = __shfl(a1[26 + k], prev, 64);

    float a2[16], d2[16];
    #pragma unroll
    for (int i = 0; i < 16; ++i) {
        float sa = 0.f, sd = 0.f;
        #pragma unroll
        for (int j = 0; j < 8; ++j) {
            const int idx = 2 * i + 1 - j;                       // [-6 .. 31]
            const float v = (idx >= 0) ? a1[idx >= 0 ? idx : 0]
                                       : h2[idx < 0 ? idx + 6 : 0];
            sa = fmaf(v, LO[j], sa);
            sd = fmaf(v, HI[j], sd);
        }
        a2[i] = sa; d2[i] = sd;
    }

    // ---- Level 3 DWT: a2(16) -> d3(8) only (a3 is zeroed by the reference)
    float h3[6];
    #pragma unroll
    for (int k = 0; k < 6; ++k) h3[k] = __shfl(a2[10 + k], prev, 64);

    float d3[8];
    #pragma unroll
    for (int i = 0; i < 8; ++i) {
        float sd = 0.f;
        #pragma unroll
        for (int j = 0; j < 8; ++j) {
            const int idx = 2 * i + 1 - j;                       // [-6 .. 15]
            const float v = (idx >= 0) ? a2[idx >= 0 ? idx : 0]
                                       : h3[idx < 0 ? idx + 6 : 0];
            sd = fmaf(v, HI[j], sd);
        }
        d3[i] = sd;
    }

    // ---- Inverse level 3: (cA=0, cD=d3) -> x2(16)
    // out[2m] = sum_q cD[m+q]*HI[2q+1] ; out[2m+1] = sum_q cD[m+q]*HI[2q]
    float hd3[3];
    #pragma unroll
    for (int k = 0; k < 3; ++k) hd3[k] = __shfl(d3[k], next, 64);

    float x2[16];
    #pragma unroll
    for (int m = 0; m < 8; ++m) {
        float e0 = 0.f, e1 = 0.f;
        #pragma unroll
        for (int q = 0; q < 4; ++q) {
            const int idx = m + q;                                // [0 .. 10]
            const float v = (idx < 8) ? d3[idx < 8 ? idx : 0]
                                      : hd3[idx >= 8 ? idx - 8 : 0];
            e0 = fmaf(v, HI[2 * q + 1], e0);
            e1 = fmaf(v, HI[2 * q],     e1);
        }
        x2[2 * m] = e0; x2[2 * m + 1] = e1;
    }

    // ---- Inverse level 2: (cA=x2, cD=d2) -> x1(32)
    float hA2i[3], hD2i[3];
    #pragma unroll
    for (int k = 0; k < 3; ++k) {
        hA2i[k] = __shfl(x2[k], next, 64);
        hD2i[k] = __shfl(d2[k], next, 64);
    }

    float x1[32];
    #pragma unroll
    for (int m = 0; m < 16; ++m) {
        float e0 = 0.f, e1 = 0.f;
        #pragma unroll
        for (int q = 0; q < 4; ++q) {
            const int idx = m + q;                                // [0 .. 18]
            const float va = (idx < 16) ? x2[idx < 16 ? idx : 0]
                                        : hA2i[idx >= 16 ? idx - 16 : 0];
            const float vd = (idx < 16) ? d2[idx < 16 ? idx : 0]
                                        : hD2i[idx >= 16 ? idx - 16 : 0];
            e0 = fmaf(va, LO[2 * q + 1], e0);
            e1 = fmaf(va, LO[2 * q],     e1);
            e0 = fmaf(vd, HI[2 * q + 1], e0);
            e1 = fmaf(vd, HI[2 * q],     e1);
        }
        x1[2 * m] = e0; x1[2 * m + 1] = e1;
    }

    // ---- Inverse level 1: (cA=x1, cD=d1) -> seasonal(64), fused residual
    float hA1i[3], hD1i[3];
    #pragma unroll
    for (int k = 0; k < 3; ++k) {
        hA1i[k] = __shfl(x1[k], next, 64);
        hD1i[k] = __shfl(d1[k], next, 64);
    }

    float* sr = seasonal + rbase;
    float* rr = residual + rbase;

    #pragma unroll
    for (int m = 0; m < 32; m += 2) {
        float s[4];
        #pragma unroll
        for (int mm = 0; mm < 2; ++mm) {
            float e0 = 0.f, e1 = 0.f;
            #pragma unroll
            for (int q = 0; q < 4; ++q) {
                const int idx = m + mm + q;                       // [0 .. 34]
                const float va = (idx < 32) ? x1[idx < 32 ? idx : 0]
                                            : hA1i[idx >= 32 ? idx - 32 : 0];
                const float vd = (idx < 32) ? d1[idx < 32 ? idx : 0]
                                            : hD1i[idx >= 32 ? idx - 32 : 0];
                e0 = fmaf(va, LO[2 * q + 1], e0);
                e1 = fmaf(va, LO[2 * q],     e1);
                e0 = fmaf(vd, HI[2 * q + 1], e0);
                e1 = fmaf(vd, HI[2 * q],     e1);
            }
            s[2 * mm]     = e0;
            s[2 * mm + 1] = e1;
        }
        const int n0 = 2 * m;                                     // output offset
        const float4 sv = make_float4(s[0], s[1], s[2], s[3]);
        const float4 rv = make_float4(x[n0 + 0] - s[0], x[n0 + 1] - s[1],
                                      x[n0 + 2] - s[2], x[n0 + 3] - s[3]);
        *(float4*)(sr + n0) = sv;
        *(float4*)(rr + n0) = rv;
    }
}

extern "C" void kernel_launch(void* const* d_in, const int* in_sizes, int n_in,
                              void* d_out, int out_size, void* d_ws, size_t ws_size,
                              hipStream_t stream) {
    const float* in = (const float*)d_in[0];
    const int rows = in_sizes[0] / 4096;   // 2048
    float* seasonal = (float*)d_out;
    float* residual = seasonal + (size_t)rows * 4096;
    // one wave per row; 4 rows per 256-thread block
    WaveletSeasonalDecomposer_43181601194295_kernel<<<dim3(rows / 4), dim3(256), 0, stream>>>(
        in, seasonal, residual);
}

// Round 3
// 93.067 us; speedup vs baseline: 1.4776x; 1.4776x over previous
//
#include <hip/hip_runtime.h>

// DB4: dec_lo[j] = h[7-j]; dec_hi[j] = (-1)^(j+1) * h[j]
static constexpr float LO[8] = {
    -0.010597401784997278f,  0.032883011666982945f,  0.030841381835986965f,
    -0.18703481171888114f,  -0.02798376941698385f,   0.6308807679295904f,
     0.7148465705525415f,    0.23037781330885523f
};
static constexpr float HI[8] = {
    -0.23037781330885523f,   0.7148465705525415f,   -0.6308807679295904f,
    -0.02798376941698385f,   0.18703481171888114f,   0.030841381835986965f,
    -0.032883011666982945f, -0.010597401784997278f
};

// Forward DWT level, periodic. Cyclic assignment: thread t computes output
// i = t + 256*m. Window x[2i-6 .. 2i+1] read as 4 aligned float2 (start even,
// lane stride = 2 floats -> 2-way LDS bank aliasing = free).
// a[i] = sum_j x[2i+1-j]*LO[j]  (x[2i+1-j] == w[7-j]); d likewise with HI.
template<int N, bool WANT_A>
__device__ __forceinline__ void fwd_level(const float* __restrict__ x,
                                          float* __restrict__ a,
                                          float* __restrict__ d,
                                          int t)
{
    constexpr int M = N / 2;
    #pragma unroll
    for (int m = 0; m < M / 256; ++m) {
        const int i = t + 256 * m;
        float w[8];
        #pragma unroll
        for (int c = 0; c < 4; ++c) {
            const int idx = (2 * i - 6 + 2 * c) & (N - 1);
            const float2 v = *(const float2*)(x + idx);
            w[2 * c] = v.x; w[2 * c + 1] = v.y;
        }
        float sa = 0.f, sd = 0.f;
        #pragma unroll
        for (int j = 0; j < 8; ++j) {
            if (WANT_A) sa = fmaf(w[7 - j], LO[j], sa);
            sd = fmaf(w[7 - j], HI[j], sd);
        }
        if (WANT_A) a[i] = sa;   // stride-1 scalar write: free
        d[i] = sd;
    }
}

// Inverse DWT level, periodic, M coeffs -> 2M outputs (LDS->LDS, inner levels).
// m = t + 256*k; out[2m] = sum_q cA[(m+q)%M]*LO[2q+1] + cD[(m+q)%M]*HI[2q+1],
// out[2m+1] uses LO[2q]/HI[2q]. Scalar reads stride-1 (free); float2 write
// stride-2 (free).
template<int M, bool HAS_A>
__device__ __forceinline__ void inv_level(const float* __restrict__ cA,
                                          const float* __restrict__ cD,
                                          float* __restrict__ out,
                                          int t)
{
    #pragma unroll
    for (int k = 0; k < M / 256; ++k) {
        const int m = t + 256 * k;
        float e0 = 0.f, e1 = 0.f;
        #pragma unroll
        for (int q = 0; q < 4; ++q) {
            const int idx = (m + q) & (M - 1);
            const float vd = cD[idx];
            e0 = fmaf(vd, HI[2 * q + 1], e0);
            e1 = fmaf(vd, HI[2 * q],     e1);
            if (HAS_A) {
                const float va = cA[idx];
                e0 = fmaf(va, LO[2 * q + 1], e0);
                e1 = fmaf(va, LO[2 * q],     e1);
            }
        }
        *(float2*)(out + 2 * m) = make_float2(e0, e1);
    }
}

// LDS arena layout (floats), 8192 * 4B = 32 KB (5 blocks/CU co-resident):
//   X  [0:4096]      dead after L1
//   A1 [4096:6144]   dead after L2
//   D1 [6144:8192]   live until final
//   A2 [0:1024]      aliases dead X
//   D2 [1024:2048]
//   D3 [2048:2560]
//   X2 [2560:3584]
//   X1 [4096:6144]   aliases dead A1
__global__ __launch_bounds__(256)
void WaveletSeasonalDecomposer_43181601194295_kernel(const float* __restrict__ in,
                                                     float* __restrict__ seasonal,
                                                     float* __restrict__ residual)
{
    __shared__ __align__(16) float arena[8192];
    const int t = threadIdx.x;
    const int row = blockIdx.x;

    const float4* in4 = (const float4*)(in + (size_t)row * 4096);
    float4 xr[4];                       // kept for fused residual (16 VGPR)
    #pragma unroll
    for (int c = 0; c < 4; ++c) {
        const float4 v = in4[t + 256 * c];
        xr[c] = v;
        ((float4*)arena)[t + 256 * c] = v;
    }
    __syncthreads();

    fwd_level<4096, true >(arena,        arena + 4096, arena + 6144, t); // X  -> A1,D1
    __syncthreads();
    fwd_level<2048, true >(arena + 4096, arena,        arena + 1024, t); // A1 -> A2,D2
    __syncthreads();
    fwd_level<1024, false>(arena,        nullptr,      arena + 2048, t); // A2 -> D3
    __syncthreads();
    inv_level<512,  false>(nullptr,       arena + 2048, arena + 2560, t); // 0,D3 -> X2
    __syncthreads();
    inv_level<1024, true >(arena + 2560,  arena + 1024, arena + 4096, t); // X2,D2 -> X1
    __syncthreads();

    // Final inverse (M=2048) fused with global store + residual.
    // Pair assignment m0 = 2t + 512k so the output float4 chunk [4t+1024k ..]
    // matches the loaded xr[k] chunk exactly. LDS reads: 3 aligned float2 per
    // array at lane stride 2 floats (free).
    const float* X1 = arena + 4096;
    const float* D1 = arena + 6144;
    float4* outS4 = (float4*)(seasonal + (size_t)row * 4096);
    float4* outR4 = (float4*)(residual + (size_t)row * 4096);
    #pragma unroll
    for (int k = 0; k < 4; ++k) {
        const int m0 = 2 * t + 512 * k;
        float av[6], dv[6];
        #pragma unroll
        for (int c = 0; c < 3; ++c) {
            const int idx = (m0 + 2 * c) & 2047;
            const float2 va = *(const float2*)(X1 + idx);
            av[2 * c] = va.x; av[2 * c + 1] = va.y;
            const float2 vd = *(const float2*)(D1 + idx);
            dv[2 * c] = vd.x; dv[2 * c + 1] = vd.y;
        }
        float s0 = 0.f, s1 = 0.f, s2 = 0.f, s3 = 0.f;
        #pragma unroll
        for (int q = 0; q < 4; ++q) {
            s0 = fmaf(av[q],     LO[2 * q + 1], s0);
            s1 = fmaf(av[q],     LO[2 * q],     s1);
            s2 = fmaf(av[q + 1], LO[2 * q + 1], s2);
            s3 = fmaf(av[q + 1], LO[2 * q],     s3);
            s0 = fmaf(dv[q],     HI[2 * q + 1], s0);
            s1 = fmaf(dv[q],     HI[2 * q],     s1);
            s2 = fmaf(dv[q + 1], HI[2 * q + 1], s2);
            s3 = fmaf(dv[q + 1], HI[2 * q],     s3);
        }
        const float4 x = xr[k];
        outS4[t + 256 * k] = make_float4(s0, s1, s2, s3);
        outR4[t + 256 * k] = make_float4(x.x - s0, x.y - s1, x.z - s2, x.w - s3);
    }
}

extern "C" void kernel_launch(void* const* d_in, const int* in_sizes, int n_in,
                              void* d_out, int out_size, void* d_ws, size_t ws_size,
                              hipStream_t stream) {
    const float* in = (const float*)d_in[0];
    const int rows = in_sizes[0] / 4096;   // 2048
    float* seasonal = (float*)d_out;
    float* residual = seasonal + (size_t)rows * 4096;
    WaveletSeasonalDecomposer_43181601194295_kernel<<<dim3(rows), dim3(256), 0, stream>>>(
        in, seasonal, residual);
}